// Round 1
// baseline (819.302 us; speedup 1.0000x reference)
//
#include <hip/hip_runtime.h>

#define F 128

__global__ void init_deg_kernel(float* __restrict__ deg, int n) {
    int i = blockIdx.x * blockDim.x + threadIdx.x;
    if (i < n) deg[i] = 1.0f;   // self loop
}

__global__ void edge_deg_kernel(const int* __restrict__ row, float* __restrict__ deg, int e) {
    int i = blockIdx.x * blockDim.x + threadIdx.x;
    if (i < e) atomicAdd(&deg[row[i]], 1.0f);
}

__global__ void dinv_kernel(float* __restrict__ deg, int n) {
    int i = blockIdx.x * blockDim.x + threadIdx.x;
    if (i < n) deg[i] = rsqrtf(deg[i]);   // deg >= 1 always (self loop)
}

// alpha[n] = sigmoid(dot(feat[n], aw) + ab); one wave (64 lanes) per node
__global__ void alpha_kernel(const float* __restrict__ feat, const float* __restrict__ aw,
                             const float* __restrict__ ab, float* __restrict__ alpha, int n) {
    int gid = blockIdx.x * blockDim.x + threadIdx.x;
    int wid = gid >> 6;
    int lane = threadIdx.x & 63;
    if (wid >= n) return;
    const float* xr = feat + (size_t)wid * F;
    float s = xr[lane] * aw[lane] + xr[lane + 64] * aw[lane + 64];
    #pragma unroll
    for (int off = 32; off > 0; off >>= 1) s += __shfl_down(s, off);
    if (lane == 0) alpha[wid] = 1.0f / (1.0f + expf(-(s + ab[0])));
}

// z_lp[row[e]][f] += dinv[row]*dinv[col] * feat[col[e]][f]; 128 threads per edge
__global__ void scatter_kernel(const float* __restrict__ feat, const int* __restrict__ row,
                               const int* __restrict__ col, const float* __restrict__ dinv,
                               float* __restrict__ zlp, int e) {
    int idx = blockIdx.x * (blockDim.x >> 7) + (threadIdx.x >> 7);
    int f = threadIdx.x & (F - 1);
    if (idx >= e) return;
    int r = row[idx], c = col[idx];
    float w = dinv[r] * dinv[c];
    atomicAdd(&zlp[(size_t)r * F + f], w * feat[(size_t)c * F + f]);
}

// z = (1-a)*x + (2a-1)*(z_lp + dinv^2 * x), in place over zlp. float4 over n*32 groups.
__global__ void combine_kernel(const float* __restrict__ feat, float* __restrict__ zlp,
                               const float* __restrict__ alpha, const float* __restrict__ dinv,
                               int n) {
    int idx = blockIdx.x * blockDim.x + threadIdx.x;
    if (idx >= n * 32) return;
    int node = idx >> 5;
    float a = alpha[node], d = dinv[node];
    float d2 = d * d;
    float ca = 1.0f - a, cb = 2.0f * a - 1.0f;
    float4 xv = ((const float4*)feat)[idx];
    float4 zv = ((float4*)zlp)[idx];
    float4 o;
    o.x = ca * xv.x + cb * (zv.x + d2 * xv.x);
    o.y = ca * xv.y + cb * (zv.y + d2 * xv.y);
    o.z = ca * xv.z + cb * (zv.z + d2 * xv.z);
    o.w = ca * xv.w + cb * (zv.w + d2 * xv.w);
    ((float4*)zlp)[idx] = o;
}

// out[n][m] = sum_k Z[n][k]*W[m][k] + bias[m]  (optionally ReLU)
// M==128: 256 threads, 8 nodes/block, each thread does 4 nodes x 1 output (reuses W row)
// M==40 : 320 threads, 8 nodes/block, each thread does 1 node x 1 output
template <int M, bool RELU>
__global__ void gemm_kernel(const float* __restrict__ Z, const float* __restrict__ W,
                            const float* __restrict__ bias, float* __restrict__ out, int n) {
    constexpr int NODES = 8;
    __shared__ float zs[NODES][F];
    int node0 = blockIdx.x * NODES;
    for (int i = threadIdx.x; i < NODES * F; i += blockDim.x) {
        int nd = node0 + (i >> 7);
        zs[i >> 7][i & (F - 1)] = (nd < n) ? Z[(size_t)nd * F + (i & (F - 1))] : 0.0f;
    }
    __syncthreads();
    if (M == 128) {
        int m = threadIdx.x & 127;
        int ng = threadIdx.x >> 7;  // 0 or 1
        const float* wr = W + (size_t)m * F;
        const float* z0 = zs[ng * 4 + 0];
        const float* z1 = zs[ng * 4 + 1];
        const float* z2 = zs[ng * 4 + 2];
        const float* z3 = zs[ng * 4 + 3];
        float a0 = 0.f, a1 = 0.f, a2 = 0.f, a3 = 0.f;
        #pragma unroll 8
        for (int k = 0; k < F; ++k) {
            float wv = wr[k];
            a0 += wv * z0[k]; a1 += wv * z1[k]; a2 += wv * z2[k]; a3 += wv * z3[k];
        }
        float b = bias[m];
        a0 += b; a1 += b; a2 += b; a3 += b;
        if (RELU) { a0 = fmaxf(a0, 0.f); a1 = fmaxf(a1, 0.f); a2 = fmaxf(a2, 0.f); a3 = fmaxf(a3, 0.f); }
        int nd = node0 + ng * 4;
        if (nd + 0 < n) out[(size_t)(nd + 0) * M + m] = a0;
        if (nd + 1 < n) out[(size_t)(nd + 1) * M + m] = a1;
        if (nd + 2 < n) out[(size_t)(nd + 2) * M + m] = a2;
        if (nd + 3 < n) out[(size_t)(nd + 3) * M + m] = a3;
    } else {
        int ln = threadIdx.x / M, m = threadIdx.x % M;
        int node = node0 + ln;
        if (node >= n) return;
        const float* wr = W + (size_t)m * F;
        const float* zr = zs[ln];
        float s = bias[m];
        #pragma unroll 8
        for (int k = 0; k < F; ++k) s += wr[k] * zr[k];
        if (RELU) s = fmaxf(s, 0.f);
        out[(size_t)node * M + m] = s;
    }
}

extern "C" void kernel_launch(void* const* d_in, const int* in_sizes, int n_in,
                              void* d_out, int out_size, void* d_ws, size_t ws_size,
                              hipStream_t stream) {
    const float* x   = (const float*)d_in[0];
    const int*   ei  = (const int*)d_in[1];
    const float* aw1 = (const float*)d_in[2];
    const float* ab1 = (const float*)d_in[3];
    const float* W1  = (const float*)d_in[4];
    const float* b1  = (const float*)d_in[5];
    const float* aw2 = (const float*)d_in[6];
    const float* ab2 = (const float*)d_in[7];
    const float* W2  = (const float*)d_in[8];
    const float* b2  = (const float*)d_in[9];
    float* out = (float*)d_out;

    int n = in_sizes[0] / F;   // 50000
    int e = in_sizes[1] / 2;   // 600000
    const int* row = ei;
    const int* col = ei + e;

    float* deg   = (float*)d_ws;              // n
    float* alpha = deg + n;                   // n
    float* zlp   = alpha + n;                 // n*F
    float* hbuf  = zlp + (size_t)n * F;       // n*F

    // degree + dinv
    init_deg_kernel<<<(n + 255) / 256, 256, 0, stream>>>(deg, n);
    edge_deg_kernel<<<(e + 255) / 256, 256, 0, stream>>>(row, deg, e);
    dinv_kernel<<<(n + 255) / 256, 256, 0, stream>>>(deg, n);
    float* dinv = deg;

    // ---- layer 1 ----
    alpha_kernel<<<(n + 3) / 4, 256, 0, stream>>>(x, aw1, ab1, alpha, n);
    hipMemsetAsync(zlp, 0, (size_t)n * F * sizeof(float), stream);
    scatter_kernel<<<(e + 1) / 2, 256, 0, stream>>>(x, row, col, dinv, zlp, e);
    combine_kernel<<<(n * 32 + 255) / 256, 256, 0, stream>>>(x, zlp, alpha, dinv, n);
    gemm_kernel<128, true><<<(n + 7) / 8, 256, 0, stream>>>(zlp, W1, b1, hbuf, n);

    // ---- layer 2 ----
    alpha_kernel<<<(n + 3) / 4, 256, 0, stream>>>(hbuf, aw2, ab2, alpha, n);
    hipMemsetAsync(zlp, 0, (size_t)n * F * sizeof(float), stream);
    scatter_kernel<<<(e + 1) / 2, 256, 0, stream>>>(hbuf, row, col, dinv, zlp, e);
    combine_kernel<<<(n * 32 + 255) / 256, 256, 0, stream>>>(hbuf, zlp, alpha, dinv, n);
    gemm_kernel<40, false><<<(n + 7) / 8, 320, 0, stream>>>(zlp, W2, b2, out, n);
}

// Round 2
// 402.825 us; speedup vs baseline: 2.0339x; 2.0339x over previous
//
#include <hip/hip_runtime.h>

#define F 128

// ---------- CSR build ----------

__global__ void hist_kernel(const int* __restrict__ row, int* __restrict__ cnt, int e) {
    int i = blockIdx.x * blockDim.x + threadIdx.x;
    if (i < e) atomicAdd(&cnt[row[i]], 1);
}

__global__ void dinv_kernel(const int* __restrict__ cnt, float* __restrict__ dinv, int n) {
    int i = blockIdx.x * blockDim.x + threadIdx.x;
    if (i < n) dinv[i] = rsqrtf((float)(cnt[i] + 1));   // +1 self loop
}

// per-block inclusive scan of cnt -> scanned (stored in rowStart slots), block sums out
__global__ void scan1_kernel(const int* __restrict__ cnt, int* __restrict__ scanned,
                             int* __restrict__ blockSums, int n) {
    __shared__ int tmp[256];
    int i = blockIdx.x * 256 + threadIdx.x;
    int v = (i < n) ? cnt[i] : 0;
    tmp[threadIdx.x] = v;
    __syncthreads();
    #pragma unroll
    for (int off = 1; off < 256; off <<= 1) {
        int t = (threadIdx.x >= off) ? tmp[threadIdx.x - off] : 0;
        __syncthreads();
        tmp[threadIdx.x] += t;
        __syncthreads();
    }
    if (i < n) scanned[i] = tmp[threadIdx.x];
    if (threadIdx.x == 255) blockSums[blockIdx.x] = tmp[255];
}

// single-block exclusive scan of block sums (nb <= 256)
__global__ void scan2_kernel(int* __restrict__ blockSums, int nb) {
    __shared__ int tmp[256];
    int v = (threadIdx.x < nb) ? blockSums[threadIdx.x] : 0;
    tmp[threadIdx.x] = v;
    __syncthreads();
    #pragma unroll
    for (int off = 1; off < 256; off <<= 1) {
        int t = (threadIdx.x >= off) ? tmp[threadIdx.x - off] : 0;
        __syncthreads();
        tmp[threadIdx.x] += t;
        __syncthreads();
    }
    if (threadIdx.x < nb) blockSums[threadIdx.x] = tmp[threadIdx.x] - v;  // exclusive
}

// rowStart[i] = inclusive[i] + blockOff - cnt[i]; rowStart[n] = total
__global__ void scan3_kernel(int* __restrict__ rowStart, const int* __restrict__ cnt,
                             const int* __restrict__ blockOff, int n) {
    int i = blockIdx.x * 256 + threadIdx.x;
    if (i >= n) return;
    int inc = rowStart[i] + blockOff[blockIdx.x];
    rowStart[i] = inc - cnt[i];
    if (i == n - 1) rowStart[n] = inc;
}

__global__ void bucket_kernel(const int* __restrict__ row, const int* __restrict__ col,
                              const int* __restrict__ rowStart, int* __restrict__ cursor,
                              const float* __restrict__ dinv, int* __restrict__ csr_col,
                              float* __restrict__ csr_w, int e) {
    int i = blockIdx.x * blockDim.x + threadIdx.x;
    if (i >= e) return;
    int r = row[i], c = col[i];
    int p = atomicAdd(&cursor[r], 1);
    int slot = rowStart[r] + p;
    csr_col[slot] = c;
    csr_w[slot] = dinv[r] * dinv[c];
}

// ---------- fused alpha + gather + self-loop + mix ----------
// one wave (64 lanes) per node; lane covers features {lane, lane+64}
__global__ void gather_kernel(const float* __restrict__ feat, const int* __restrict__ rowStart,
                              const int* __restrict__ csr_col, const float* __restrict__ csr_w,
                              const float* __restrict__ dinv, const float* __restrict__ aw,
                              const float* __restrict__ ab, float* __restrict__ z, int n) {
    int wid = (blockIdx.x * blockDim.x + threadIdx.x) >> 6;
    int lane = threadIdx.x & 63;
    if (wid >= n) return;
    const float* xr = feat + (size_t)wid * F;
    float x0 = xr[lane], x1 = xr[lane + 64];
    // alpha = sigmoid(x . aw + ab)
    float s = x0 * aw[lane] + x1 * aw[lane + 64];
    #pragma unroll
    for (int off = 32; off > 0; off >>= 1) s += __shfl_down(s, off);
    s = __shfl(s, 0);
    float a = 1.0f / (1.0f + expf(-(s + ab[0])));
    // self loop
    float d = dinv[wid];
    float acc0 = d * d * x0, acc1 = d * d * x1;
    // neighbors
    int j = rowStart[wid], en = rowStart[wid + 1];
    for (; j + 1 < en; j += 2) {
        int c0 = csr_col[j], c1 = csr_col[j + 1];
        float w0 = csr_w[j], w1 = csr_w[j + 1];
        const float* f0 = feat + (size_t)c0 * F;
        const float* f1 = feat + (size_t)c1 * F;
        acc0 += w0 * f0[lane];
        acc1 += w0 * f0[lane + 64];
        acc0 += w1 * f1[lane];
        acc1 += w1 * f1[lane + 64];
    }
    if (j < en) {
        int c0 = csr_col[j];
        float w0 = csr_w[j];
        const float* f0 = feat + (size_t)c0 * F;
        acc0 += w0 * f0[lane];
        acc1 += w0 * f0[lane + 64];
    }
    // z = (1-a)*x + (2a-1)*z_lp
    float ca = 1.0f - a, cb = 2.0f * a - 1.0f;
    z[(size_t)wid * F + lane] = ca * x0 + cb * acc0;
    z[(size_t)wid * F + 64 + lane] = ca * x1 + cb * acc1;
}

// ---------- dense layers ----------
// out[n][m] = sum_k Z[n][k]*W[m][k] + bias[m]  (optionally ReLU)
template <int M, bool RELU>
__global__ void gemm_kernel(const float* __restrict__ Z, const float* __restrict__ W,
                            const float* __restrict__ bias, float* __restrict__ out, int n) {
    constexpr int NODES = 8;
    __shared__ float zs[NODES][F];
    int node0 = blockIdx.x * NODES;
    for (int i = threadIdx.x; i < NODES * F; i += blockDim.x) {
        int nd = node0 + (i >> 7);
        zs[i >> 7][i & (F - 1)] = (nd < n) ? Z[(size_t)nd * F + (i & (F - 1))] : 0.0f;
    }
    __syncthreads();
    if (M == 128) {
        int m = threadIdx.x & 127;
        int ng = threadIdx.x >> 7;  // 0 or 1
        const float* wr = W + (size_t)m * F;
        const float* z0 = zs[ng * 4 + 0];
        const float* z1 = zs[ng * 4 + 1];
        const float* z2 = zs[ng * 4 + 2];
        const float* z3 = zs[ng * 4 + 3];
        float a0 = 0.f, a1 = 0.f, a2 = 0.f, a3 = 0.f;
        #pragma unroll 8
        for (int k = 0; k < F; ++k) {
            float wv = wr[k];
            a0 += wv * z0[k]; a1 += wv * z1[k]; a2 += wv * z2[k]; a3 += wv * z3[k];
        }
        float b = bias[m];
        a0 += b; a1 += b; a2 += b; a3 += b;
        if (RELU) { a0 = fmaxf(a0, 0.f); a1 = fmaxf(a1, 0.f); a2 = fmaxf(a2, 0.f); a3 = fmaxf(a3, 0.f); }
        int nd = node0 + ng * 4;
        if (nd + 0 < n) out[(size_t)(nd + 0) * M + m] = a0;
        if (nd + 1 < n) out[(size_t)(nd + 1) * M + m] = a1;
        if (nd + 2 < n) out[(size_t)(nd + 2) * M + m] = a2;
        if (nd + 3 < n) out[(size_t)(nd + 3) * M + m] = a3;
    } else {
        int ln = threadIdx.x / M, m = threadIdx.x % M;
        int node = node0 + ln;
        if (node >= n) return;
        const float* wr = W + (size_t)m * F;
        const float* zr = zs[ln];
        float s = bias[m];
        #pragma unroll 8
        for (int k = 0; k < F; ++k) s += wr[k] * zr[k];
        if (RELU) s = fmaxf(s, 0.f);
        out[(size_t)node * M + m] = s;
    }
}

extern "C" void kernel_launch(void* const* d_in, const int* in_sizes, int n_in,
                              void* d_out, int out_size, void* d_ws, size_t ws_size,
                              hipStream_t stream) {
    const float* x   = (const float*)d_in[0];
    const int*   ei  = (const int*)d_in[1];
    const float* aw1 = (const float*)d_in[2];
    const float* ab1 = (const float*)d_in[3];
    const float* W1  = (const float*)d_in[4];
    const float* b1  = (const float*)d_in[5];
    const float* aw2 = (const float*)d_in[6];
    const float* ab2 = (const float*)d_in[7];
    const float* W2  = (const float*)d_in[8];
    const float* b2  = (const float*)d_in[9];
    float* out = (float*)d_out;

    int n = in_sizes[0] / F;   // 50000
    int e = in_sizes[1] / 2;   // 600000
    const int* row = ei;
    const int* col = ei + e;

    // workspace layout (4B elements)
    char* p = (char*)d_ws;
    int*   cnt      = (int*)p;            p += (size_t)n * 4;        // also reused as cursor
    int*   rowStart = (int*)p;            p += (size_t)(n + 2) * 4;
    int*   blockSums= (int*)p;            p += 256 * 4;
    int*   csr_col  = (int*)p;            p += (size_t)e * 4;
    float* dinv     = (float*)p;          p += (size_t)n * 4;
    float* csr_w    = (float*)p;          p += (size_t)e * 4;
    float* zlp      = (float*)p;          p += (size_t)n * F * 4;
    float* hbuf     = (float*)p;

    int nb = (n + 255) / 256;  // 196 <= 256

    // ---- CSR build (shared by both layers) ----
    hipMemsetAsync(cnt, 0, (size_t)n * 4, stream);
    hist_kernel<<<(e + 255) / 256, 256, 0, stream>>>(row, cnt, e);
    dinv_kernel<<<nb, 256, 0, stream>>>(cnt, dinv, n);
    scan1_kernel<<<nb, 256, 0, stream>>>(cnt, rowStart, blockSums, n);
    scan2_kernel<<<1, 256, 0, stream>>>(blockSums, nb);
    scan3_kernel<<<nb, 256, 0, stream>>>(rowStart, cnt, blockSums, n);
    hipMemsetAsync(cnt, 0, (size_t)n * 4, stream);  // cursor
    bucket_kernel<<<(e + 255) / 256, 256, 0, stream>>>(row, col, rowStart, cnt, dinv,
                                                       csr_col, csr_w, e);

    // ---- layer 1 ----
    gather_kernel<<<(n + 3) / 4, 256, 0, stream>>>(x, rowStart, csr_col, csr_w, dinv,
                                                   aw1, ab1, zlp, n);
    gemm_kernel<128, true><<<(n + 7) / 8, 256, 0, stream>>>(zlp, W1, b1, hbuf, n);

    // ---- layer 2 ----
    gather_kernel<<<(n + 3) / 4, 256, 0, stream>>>(hbuf, rowStart, csr_col, csr_w, dinv,
                                                   aw2, ab2, zlp, n);
    gemm_kernel<40, false><<<(n + 7) / 8, 320, 0, stream>>>(zlp, W2, b2, out, n);
}

// Round 3
// 261.739 us; speedup vs baseline: 3.1302x; 1.5390x over previous
//
#include <hip/hip_runtime.h>

#define F 128

// ---------- CSR build ----------

__global__ void hist_kernel(const int* __restrict__ row, int* __restrict__ cnt, int e) {
    int i = blockIdx.x * blockDim.x + threadIdx.x;
    if (i < e) atomicAdd(&cnt[row[i]], 1);
}

__global__ void dinv_kernel(const int* __restrict__ cnt, float* __restrict__ dinv, int n) {
    int i = blockIdx.x * blockDim.x + threadIdx.x;
    if (i < n) dinv[i] = rsqrtf((float)(cnt[i] + 1));   // +1 self loop
}

// per-block inclusive scan of cnt -> scanned (stored in rowStart slots), block sums out
__global__ void scan1_kernel(const int* __restrict__ cnt, int* __restrict__ scanned,
                             int* __restrict__ blockSums, int n) {
    __shared__ int tmp[256];
    int i = blockIdx.x * 256 + threadIdx.x;
    int v = (i < n) ? cnt[i] : 0;
    tmp[threadIdx.x] = v;
    __syncthreads();
    #pragma unroll
    for (int off = 1; off < 256; off <<= 1) {
        int t = (threadIdx.x >= off) ? tmp[threadIdx.x - off] : 0;
        __syncthreads();
        tmp[threadIdx.x] += t;
        __syncthreads();
    }
    if (i < n) scanned[i] = tmp[threadIdx.x];
    if (threadIdx.x == 255) blockSums[blockIdx.x] = tmp[255];
}

// single-block exclusive scan of block sums (nb <= 256)
__global__ void scan2_kernel(int* __restrict__ blockSums, int nb) {
    __shared__ int tmp[256];
    int v = (threadIdx.x < nb) ? blockSums[threadIdx.x] : 0;
    tmp[threadIdx.x] = v;
    __syncthreads();
    #pragma unroll
    for (int off = 1; off < 256; off <<= 1) {
        int t = (threadIdx.x >= off) ? tmp[threadIdx.x - off] : 0;
        __syncthreads();
        tmp[threadIdx.x] += t;
        __syncthreads();
    }
    if (threadIdx.x < nb) blockSums[threadIdx.x] = tmp[threadIdx.x] - v;  // exclusive
}

// rowStart[i] = inclusive[i] + blockOff - cnt[i]; rowStart[n] = total
__global__ void scan3_kernel(int* __restrict__ rowStart, const int* __restrict__ cnt,
                             const int* __restrict__ blockOff, int n) {
    int i = blockIdx.x * 256 + threadIdx.x;
    if (i >= n) return;
    int inc = rowStart[i] + blockOff[blockIdx.x];
    rowStart[i] = inc - cnt[i];
    if (i == n - 1) rowStart[n] = inc;
}

__global__ void bucket_kernel(const int* __restrict__ row, const int* __restrict__ col,
                              const int* __restrict__ rowStart, int* __restrict__ cursor,
                              const float* __restrict__ dinv, int* __restrict__ csr_col,
                              float* __restrict__ csr_w, int e) {
    int i = blockIdx.x * blockDim.x + threadIdx.x;
    if (i >= e) return;
    int r = row[i], c = col[i];
    int p = atomicAdd(&cursor[r], 1);
    int slot = rowStart[r] + p;
    csr_col[slot] = c;
    csr_w[slot] = dinv[r] * dinv[c];
}

// W[M][128] -> Wt[128][M]
__global__ void transpose_w_kernel(const float* __restrict__ W, float* __restrict__ Wt, int M) {
    int i = blockIdx.x * blockDim.x + threadIdx.x;
    if (i < M * F) {
        int m = i >> 7, k = i & (F - 1);
        Wt[k * M + m] = W[i];
    }
}

// ---------- fused alpha + gather + self-loop + mix ----------
// one wave (64 lanes) per node; lane covers features {lane, lane+64}
__global__ void gather_kernel(const float* __restrict__ feat, const int* __restrict__ rowStart,
                              const int* __restrict__ csr_col, const float* __restrict__ csr_w,
                              const float* __restrict__ dinv, const float* __restrict__ aw,
                              const float* __restrict__ ab, float* __restrict__ z, int n) {
    int wid = (blockIdx.x * blockDim.x + threadIdx.x) >> 6;
    int lane = threadIdx.x & 63;
    if (wid >= n) return;
    const float* xr = feat + (size_t)wid * F;
    float x0 = xr[lane], x1 = xr[lane + 64];
    // alpha = sigmoid(x . aw + ab)
    float s = x0 * aw[lane] + x1 * aw[lane + 64];
    #pragma unroll
    for (int off = 32; off > 0; off >>= 1) s += __shfl_down(s, off);
    s = __shfl(s, 0);
    float a = 1.0f / (1.0f + expf(-(s + ab[0])));
    // self loop
    float d = dinv[wid];
    float acc0 = d * d * x0, acc1 = d * d * x1;
    // neighbors
    int j = rowStart[wid], en = rowStart[wid + 1];
    for (; j + 1 < en; j += 2) {
        int c0 = csr_col[j], c1 = csr_col[j + 1];
        float w0 = csr_w[j], w1 = csr_w[j + 1];
        const float* f0 = feat + (size_t)c0 * F;
        const float* f1 = feat + (size_t)c1 * F;
        acc0 += w0 * f0[lane];
        acc1 += w0 * f0[lane + 64];
        acc0 += w1 * f1[lane];
        acc1 += w1 * f1[lane + 64];
    }
    if (j < en) {
        int c0 = csr_col[j];
        float w0 = csr_w[j];
        const float* f0 = feat + (size_t)c0 * F;
        acc0 += w0 * f0[lane];
        acc1 += w0 * f0[lane + 64];
    }
    // z = (1-a)*x + (2a-1)*z_lp
    float ca = 1.0f - a, cb = 2.0f * a - 1.0f;
    z[(size_t)wid * F + lane] = ca * x0 + cb * acc0;
    z[(size_t)wid * F + 64 + lane] = ca * x1 + cb * acc1;
}

// ---------- dense layers (register-tiled) ----------
// out[n][m] = sum_k Z[n][k]*Wt[k][m] + bias[m]  (optionally ReLU)
// Thread layout: mt = tid % MT (m-tile of 4 outputs), ng = tid / MT (node group of NPG nodes).
// Block covers NODES = (blockDim/MT)*NPG = 64 nodes. zs padded to 132 floats/row.
template <int M, int MT, int NPG, bool RELU>
__global__ void gemm_kernel(const float* __restrict__ Z, const float* __restrict__ Wt,
                            const float* __restrict__ bias, float* __restrict__ out, int n) {
    constexpr int NODES = 64;
    constexpr int LD = F + 4;  // 132 floats: row stride 528B = 33*16B (b128-aligned, bank-skewed)
    __shared__ float zs[NODES * LD];
    int node0 = blockIdx.x * NODES;
    // stage Z tile (vector loads)
    for (int i = threadIdx.x; i < NODES * (F / 4); i += blockDim.x) {
        int nd = i >> 5, f4 = i & 31;
        float4 v = make_float4(0.f, 0.f, 0.f, 0.f);
        if (node0 + nd < n) v = ((const float4*)(Z + (size_t)(node0 + nd) * F))[f4];
        *(float4*)&zs[nd * LD + f4 * 4] = v;
    }
    __syncthreads();

    int mt = threadIdx.x % MT;
    int ng = threadIdx.x / MT;
    int m0 = mt * 4;

    float4 acc[NPG];
    #pragma unroll
    for (int i = 0; i < NPG; ++i) acc[i] = make_float4(0.f, 0.f, 0.f, 0.f);

    #pragma unroll 2
    for (int kt = 0; kt < F / 4; ++kt) {
        int k = kt * 4;
        float4 w0 = *(const float4*)&Wt[(size_t)(k + 0) * M + m0];
        float4 w1 = *(const float4*)&Wt[(size_t)(k + 1) * M + m0];
        float4 w2 = *(const float4*)&Wt[(size_t)(k + 2) * M + m0];
        float4 w3 = *(const float4*)&Wt[(size_t)(k + 3) * M + m0];
        #pragma unroll
        for (int i = 0; i < NPG; ++i) {
            float4 zv = *(const float4*)&zs[(ng * NPG + i) * LD + k];
            acc[i].x += zv.x * w0.x + zv.y * w1.x + zv.z * w2.x + zv.w * w3.x;
            acc[i].y += zv.x * w0.y + zv.y * w1.y + zv.z * w2.y + zv.w * w3.y;
            acc[i].z += zv.x * w0.z + zv.y * w1.z + zv.z * w2.z + zv.w * w3.z;
            acc[i].w += zv.x * w0.w + zv.y * w1.w + zv.z * w2.w + zv.w * w3.w;
        }
    }

    float4 b4 = *(const float4*)&bias[m0];
    #pragma unroll
    for (int i = 0; i < NPG; ++i) {
        int node = node0 + ng * NPG + i;
        if (node >= n) continue;
        float4 o;
        o.x = acc[i].x + b4.x; o.y = acc[i].y + b4.y;
        o.z = acc[i].z + b4.z; o.w = acc[i].w + b4.w;
        if (RELU) {
            o.x = fmaxf(o.x, 0.f); o.y = fmaxf(o.y, 0.f);
            o.z = fmaxf(o.z, 0.f); o.w = fmaxf(o.w, 0.f);
        }
        *(float4*)&out[(size_t)node * M + m0] = o;
    }
}

extern "C" void kernel_launch(void* const* d_in, const int* in_sizes, int n_in,
                              void* d_out, int out_size, void* d_ws, size_t ws_size,
                              hipStream_t stream) {
    const float* x   = (const float*)d_in[0];
    const int*   ei  = (const int*)d_in[1];
    const float* aw1 = (const float*)d_in[2];
    const float* ab1 = (const float*)d_in[3];
    const float* W1  = (const float*)d_in[4];
    const float* b1  = (const float*)d_in[5];
    const float* aw2 = (const float*)d_in[6];
    const float* ab2 = (const float*)d_in[7];
    const float* W2  = (const float*)d_in[8];
    const float* b2  = (const float*)d_in[9];
    float* out = (float*)d_out;

    int n = in_sizes[0] / F;   // 50000
    int e = in_sizes[1] / 2;   // 600000
    const int* row = ei;
    const int* col = ei + e;

    // workspace layout (4B elements)
    char* p = (char*)d_ws;
    int*   cnt      = (int*)p;            p += (size_t)n * 4;        // also reused as cursor
    int*   rowStart = (int*)p;            p += (size_t)(n + 2) * 4;
    int*   blockSums= (int*)p;            p += 256 * 4;
    int*   csr_col  = (int*)p;            p += (size_t)e * 4;
    float* dinv     = (float*)p;          p += (size_t)n * 4;
    float* csr_w    = (float*)p;          p += (size_t)e * 4;
    float* wt1      = (float*)p;          p += (size_t)F * F * 4;    // Wt1[128][128]
    float* wt2      = (float*)p;          p += (size_t)F * 40 * 4;   // Wt2[128][40]
    float* zlp      = (float*)p;          p += (size_t)n * F * 4;
    float* hbuf     = (float*)p;

    int nb = (n + 255) / 256;  // 196 <= 256

    // ---- CSR build (shared by both layers) + W transposes ----
    hipMemsetAsync(cnt, 0, (size_t)n * 4, stream);
    hist_kernel<<<(e + 255) / 256, 256, 0, stream>>>(row, cnt, e);
    dinv_kernel<<<nb, 256, 0, stream>>>(cnt, dinv, n);
    scan1_kernel<<<nb, 256, 0, stream>>>(cnt, rowStart, blockSums, n);
    scan2_kernel<<<1, 256, 0, stream>>>(blockSums, nb);
    scan3_kernel<<<nb, 256, 0, stream>>>(rowStart, cnt, blockSums, n);
    hipMemsetAsync(cnt, 0, (size_t)n * 4, stream);  // cursor
    bucket_kernel<<<(e + 255) / 256, 256, 0, stream>>>(row, col, rowStart, cnt, dinv,
                                                       csr_col, csr_w, e);
    transpose_w_kernel<<<(F * F + 255) / 256, 256, 0, stream>>>(W1, wt1, F);
    transpose_w_kernel<<<(40 * F + 255) / 256, 256, 0, stream>>>(W2, wt2, 40);

    int gblk = (n + 63) / 64;  // 782

    // ---- layer 1 ----
    gather_kernel<<<(n + 3) / 4, 256, 0, stream>>>(x, rowStart, csr_col, csr_w, dinv,
                                                   aw1, ab1, zlp, n);
    gemm_kernel<128, 32, 8, true><<<gblk, 256, 0, stream>>>(zlp, wt1, b1, hbuf, n);

    // ---- layer 2 ----
    gather_kernel<<<(n + 3) / 4, 256, 0, stream>>>(hbuf, rowStart, csr_col, csr_w, dinv,
                                                   aw2, ab2, zlp, n);
    gemm_kernel<40, 10, 2, false><<<gblk, 320, 0, stream>>>(zlp, wt2, b2, out, n);
}

// Round 4
// 234.485 us; speedup vs baseline: 3.4940x; 1.1162x over previous
//
#include <hip/hip_runtime.h>

#define F 128

// ---------- CSR build ----------

__global__ void hist_kernel(const int* __restrict__ row, int* __restrict__ cnt, int e) {
    int i = blockIdx.x * blockDim.x + threadIdx.x;
    if (i < e) atomicAdd(&cnt[row[i]], 1);
}

__global__ void dinv_kernel(const int* __restrict__ cnt, float* __restrict__ dinv, int n) {
    int i = blockIdx.x * blockDim.x + threadIdx.x;
    if (i < n) dinv[i] = rsqrtf((float)(cnt[i] + 1));   // +1 self loop
}

// per-block inclusive scan of cnt -> scanned (stored in rowStart slots), block sums out
__global__ void scan1_kernel(const int* __restrict__ cnt, int* __restrict__ scanned,
                             int* __restrict__ blockSums, int n) {
    __shared__ int tmp[256];
    int i = blockIdx.x * 256 + threadIdx.x;
    int v = (i < n) ? cnt[i] : 0;
    tmp[threadIdx.x] = v;
    __syncthreads();
    #pragma unroll
    for (int off = 1; off < 256; off <<= 1) {
        int t = (threadIdx.x >= off) ? tmp[threadIdx.x - off] : 0;
        __syncthreads();
        tmp[threadIdx.x] += t;
        __syncthreads();
    }
    if (i < n) scanned[i] = tmp[threadIdx.x];
    if (threadIdx.x == 255) blockSums[blockIdx.x] = tmp[255];
}

// single-block exclusive scan of block sums (nb <= 256)
__global__ void scan2_kernel(int* __restrict__ blockSums, int nb) {
    __shared__ int tmp[256];
    int v = (threadIdx.x < nb) ? blockSums[threadIdx.x] : 0;
    tmp[threadIdx.x] = v;
    __syncthreads();
    #pragma unroll
    for (int off = 1; off < 256; off <<= 1) {
        int t = (threadIdx.x >= off) ? tmp[threadIdx.x - off] : 0;
        __syncthreads();
        tmp[threadIdx.x] += t;
        __syncthreads();
    }
    if (threadIdx.x < nb) blockSums[threadIdx.x] = tmp[threadIdx.x] - v;  // exclusive
}

// rowStart[i] = inclusive[i] + blockOff - cnt[i]; rowStart[n] = total
__global__ void scan3_kernel(int* __restrict__ rowStart, const int* __restrict__ cnt,
                             const int* __restrict__ blockOff, int n) {
    int i = blockIdx.x * 256 + threadIdx.x;
    if (i >= n) return;
    int inc = rowStart[i] + blockOff[blockIdx.x];
    rowStart[i] = inc - cnt[i];
    if (i == n - 1) rowStart[n] = inc;
}

__global__ void bucket_kernel(const int* __restrict__ row, const int* __restrict__ col,
                              const int* __restrict__ rowStart, int* __restrict__ cursor,
                              const float* __restrict__ dinv, int* __restrict__ csr_col,
                              float* __restrict__ csr_w, int e) {
    int i = blockIdx.x * blockDim.x + threadIdx.x;
    if (i >= e) return;
    int r = row[i], c = col[i];
    int p = atomicAdd(&cursor[r], 1);
    int slot = rowStart[r] + p;
    csr_col[slot] = c;
    csr_w[slot] = dinv[r] * dinv[c];
}

// W[M][128] -> Wt[128][M]
__global__ void transpose_w_kernel(const float* __restrict__ W, float* __restrict__ Wt, int M) {
    int i = blockIdx.x * blockDim.x + threadIdx.x;
    if (i < M * F) {
        int m = i >> 7, k = i & (F - 1);
        Wt[k * M + m] = W[i];
    }
}

// ---------- fused alpha + gather + self-loop + mix (128-dim) ----------
// one wave per node; lane covers features {2*lane, 2*lane+1} (float2)
__global__ void gather_kernel(const float* __restrict__ feat, const int* __restrict__ rowStart,
                              const int* __restrict__ csr_col, const float* __restrict__ csr_w,
                              const float* __restrict__ dinv, const float* __restrict__ aw,
                              const float* __restrict__ ab, float* __restrict__ z, int n) {
    int wid = (blockIdx.x * blockDim.x + threadIdx.x) >> 6;
    int lane = threadIdx.x & 63;
    if (wid >= n) return;
    float2 xv = ((const float2*)(feat + (size_t)wid * F))[lane];
    float2 awv = ((const float2*)aw)[lane];
    // alpha = sigmoid(x . aw + ab)
    float s = xv.x * awv.x + xv.y * awv.y;
    #pragma unroll
    for (int off = 32; off > 0; off >>= 1) s += __shfl_down(s, off);
    s = __shfl(s, 0);
    float a = 1.0f / (1.0f + expf(-(s + ab[0])));
    // self loop
    float d = dinv[wid];
    float2 acc;
    acc.x = d * d * xv.x;
    acc.y = d * d * xv.y;
    // neighbors (4-edge unroll for MLP)
    int j = rowStart[wid], en = rowStart[wid + 1];
    for (; j + 3 < en; j += 4) {
        int c0 = csr_col[j], c1 = csr_col[j + 1], c2 = csr_col[j + 2], c3 = csr_col[j + 3];
        float w0 = csr_w[j], w1 = csr_w[j + 1], w2 = csr_w[j + 2], w3 = csr_w[j + 3];
        float2 f0 = ((const float2*)(feat + (size_t)c0 * F))[lane];
        float2 f1 = ((const float2*)(feat + (size_t)c1 * F))[lane];
        float2 f2 = ((const float2*)(feat + (size_t)c2 * F))[lane];
        float2 f3 = ((const float2*)(feat + (size_t)c3 * F))[lane];
        acc.x += w0 * f0.x; acc.y += w0 * f0.y;
        acc.x += w1 * f1.x; acc.y += w1 * f1.y;
        acc.x += w2 * f2.x; acc.y += w2 * f2.y;
        acc.x += w3 * f3.x; acc.y += w3 * f3.y;
    }
    for (; j < en; ++j) {
        int c0 = csr_col[j];
        float w0 = csr_w[j];
        float2 f0 = ((const float2*)(feat + (size_t)c0 * F))[lane];
        acc.x += w0 * f0.x; acc.y += w0 * f0.y;
    }
    // z = (1-a)*x + (2a-1)*z_lp
    float ca = 1.0f - a, cb = 2.0f * a - 1.0f;
    float2 o;
    o.x = ca * xv.x + cb * acc.x;
    o.y = ca * xv.y + cb * acc.y;
    ((float2*)(z + (size_t)wid * F))[lane] = o;
}

// ---------- gather on 40-dim projected features + mix + bias (final output) ----------
__global__ void gather40_kernel(const float* __restrict__ y, const int* __restrict__ rowStart,
                                const int* __restrict__ csr_col, const float* __restrict__ csr_w,
                                const float* __restrict__ dinv, const float* __restrict__ alpha,
                                const float* __restrict__ bias, float* __restrict__ out, int n) {
    int wid = (blockIdx.x * blockDim.x + threadIdx.x) >> 6;
    int lane = threadIdx.x & 63;
    if (wid >= n || lane >= 40) return;
    float yv = y[(size_t)wid * 40 + lane];
    float d = dinv[wid];
    float acc = d * d * yv;
    int j = rowStart[wid], en = rowStart[wid + 1];
    for (; j + 3 < en; j += 4) {
        int c0 = csr_col[j], c1 = csr_col[j + 1], c2 = csr_col[j + 2], c3 = csr_col[j + 3];
        float w0 = csr_w[j], w1 = csr_w[j + 1], w2 = csr_w[j + 2], w3 = csr_w[j + 3];
        acc += w0 * y[(size_t)c0 * 40 + lane];
        acc += w1 * y[(size_t)c1 * 40 + lane];
        acc += w2 * y[(size_t)c2 * 40 + lane];
        acc += w3 * y[(size_t)c3 * 40 + lane];
    }
    for (; j < en; ++j) {
        acc += csr_w[j] * y[(size_t)csr_col[j] * 40 + lane];
    }
    float a = alpha[wid];
    out[(size_t)wid * 40 + lane] = (1.0f - a) * yv + (2.0f * a - 1.0f) * acc + bias[lane];
}

// ---------- dense layers (register-tiled) ----------
// out[n][m] = sum_k Z[n][k]*Wt[k][m] (+ bias[m]) (+ ReLU)
// If ALPHA: also emits alphaOut[node] = sigmoid(out_row . aw + ab) (requires MT==32).
template <int M, int MT, int NPG, bool RELU, bool BIAS, bool ALPHA>
__global__ void gemm_kernel(const float* __restrict__ Z, const float* __restrict__ Wt,
                            const float* __restrict__ bias, float* __restrict__ out,
                            const float* __restrict__ aw, const float* __restrict__ ab,
                            float* __restrict__ alphaOut, int n) {
    constexpr int NODES = 64;
    constexpr int LD = F + 4;  // 132 floats: row stride 528B (b128-aligned, bank-skewed)
    __shared__ float zs[NODES * LD];
    int node0 = blockIdx.x * NODES;
    for (int i = threadIdx.x; i < NODES * (F / 4); i += blockDim.x) {
        int nd = i >> 5, f4 = i & 31;
        float4 v = make_float4(0.f, 0.f, 0.f, 0.f);
        if (node0 + nd < n) v = ((const float4*)(Z + (size_t)(node0 + nd) * F))[f4];
        *(float4*)&zs[nd * LD + f4 * 4] = v;
    }
    __syncthreads();

    int mt = threadIdx.x % MT;
    int ng = threadIdx.x / MT;
    int m0 = mt * 4;

    float4 acc[NPG];
    #pragma unroll
    for (int i = 0; i < NPG; ++i) acc[i] = make_float4(0.f, 0.f, 0.f, 0.f);

    #pragma unroll 2
    for (int kt = 0; kt < F / 4; ++kt) {
        int k = kt * 4;
        float4 w0 = *(const float4*)&Wt[(size_t)(k + 0) * M + m0];
        float4 w1 = *(const float4*)&Wt[(size_t)(k + 1) * M + m0];
        float4 w2 = *(const float4*)&Wt[(size_t)(k + 2) * M + m0];
        float4 w3 = *(const float4*)&Wt[(size_t)(k + 3) * M + m0];
        #pragma unroll
        for (int i = 0; i < NPG; ++i) {
            float4 zv = *(const float4*)&zs[(ng * NPG + i) * LD + k];
            acc[i].x += zv.x * w0.x + zv.y * w1.x + zv.z * w2.x + zv.w * w3.x;
            acc[i].y += zv.x * w0.y + zv.y * w1.y + zv.z * w2.y + zv.w * w3.y;
            acc[i].z += zv.x * w0.z + zv.y * w1.z + zv.z * w2.z + zv.w * w3.z;
            acc[i].w += zv.x * w0.w + zv.y * w1.w + zv.z * w2.w + zv.w * w3.w;
        }
    }

    float4 b4 = make_float4(0.f, 0.f, 0.f, 0.f);
    if (BIAS) b4 = *(const float4*)&bias[m0];
    float4 awv = make_float4(0.f, 0.f, 0.f, 0.f);
    if (ALPHA) awv = *(const float4*)&aw[m0];
    float asum[NPG];

    #pragma unroll
    for (int i = 0; i < NPG; ++i) {
        int node = node0 + ng * NPG + i;
        float4 o;
        o.x = acc[i].x + b4.x; o.y = acc[i].y + b4.y;
        o.z = acc[i].z + b4.z; o.w = acc[i].w + b4.w;
        if (RELU) {
            o.x = fmaxf(o.x, 0.f); o.y = fmaxf(o.y, 0.f);
            o.z = fmaxf(o.z, 0.f); o.w = fmaxf(o.w, 0.f);
        }
        if (ALPHA) asum[i] = o.x * awv.x + o.y * awv.y + o.z * awv.z + o.w * awv.w;
        if (node < n) *(float4*)&out[(size_t)node * M + m0] = o;
    }

    if (ALPHA) {
        // MT==32: the 32 threads sharing ng form one half-wave -> shfl_xor reduce
        #pragma unroll
        for (int i = 0; i < NPG; ++i) {
            float s = asum[i];
            #pragma unroll
            for (int off = 16; off > 0; off >>= 1) s += __shfl_xor(s, off);
            if (mt == 0) {
                int node = node0 + ng * NPG + i;
                if (node < n) alphaOut[node] = 1.0f / (1.0f + expf(-(s + ab[0])));
            }
        }
    }
}

extern "C" void kernel_launch(void* const* d_in, const int* in_sizes, int n_in,
                              void* d_out, int out_size, void* d_ws, size_t ws_size,
                              hipStream_t stream) {
    const float* x   = (const float*)d_in[0];
    const int*   ei  = (const int*)d_in[1];
    const float* aw1 = (const float*)d_in[2];
    const float* ab1 = (const float*)d_in[3];
    const float* W1  = (const float*)d_in[4];
    const float* b1  = (const float*)d_in[5];
    const float* aw2 = (const float*)d_in[6];
    const float* ab2 = (const float*)d_in[7];
    const float* W2  = (const float*)d_in[8];
    const float* b2  = (const float*)d_in[9];
    float* out = (float*)d_out;

    int n = in_sizes[0] / F;   // 50000
    int e = in_sizes[1] / 2;   // 600000
    const int* row = ei;
    const int* col = ei + e;

    // workspace layout (4B elements)
    char* p = (char*)d_ws;
    int*   cnt      = (int*)p;            p += (size_t)n * 4;        // also reused as cursor
    int*   rowStart = (int*)p;            p += (size_t)(n + 2) * 4;
    int*   blockSums= (int*)p;            p += 256 * 4;
    int*   csr_col  = (int*)p;            p += (size_t)e * 4;
    float* dinv     = (float*)p;          p += (size_t)n * 4;
    float* csr_w    = (float*)p;          p += (size_t)e * 4;
    float* wt1      = (float*)p;          p += (size_t)F * F * 4;    // Wt1[128][128]
    float* wt2      = (float*)p;          p += (size_t)F * 40 * 4;   // Wt2[128][40]
    float* zlp      = (float*)p;          p += (size_t)n * F * 4;    // z (layer1) / y (layer2)
    float* hbuf     = (float*)p;          p += (size_t)n * F * 4;
    float* alpha2   = (float*)p;

    int nb = (n + 255) / 256;  // 196 <= 256

    // ---- CSR build (shared by both layers) + W transposes ----
    hipMemsetAsync(cnt, 0, (size_t)n * 4, stream);
    hist_kernel<<<(e + 255) / 256, 256, 0, stream>>>(row, cnt, e);
    dinv_kernel<<<nb, 256, 0, stream>>>(cnt, dinv, n);
    scan1_kernel<<<nb, 256, 0, stream>>>(cnt, rowStart, blockSums, n);
    scan2_kernel<<<1, 256, 0, stream>>>(blockSums, nb);
    scan3_kernel<<<nb, 256, 0, stream>>>(rowStart, cnt, blockSums, n);
    hipMemsetAsync(cnt, 0, (size_t)n * 4, stream);  // cursor
    bucket_kernel<<<(e + 255) / 256, 256, 0, stream>>>(row, col, rowStart, cnt, dinv,
                                                       csr_col, csr_w, e);
    transpose_w_kernel<<<(F * F + 255) / 256, 256, 0, stream>>>(W1, wt1, F);
    transpose_w_kernel<<<(40 * F + 255) / 256, 256, 0, stream>>>(W2, wt2, 40);

    int gblk = (n + 63) / 64;  // 782

    // ---- layer 1: gather(x) -> z; h = relu(z@W1t + b1); alpha2 = sigmoid(h.aw2+ab2) ----
    gather_kernel<<<(n + 3) / 4, 256, 0, stream>>>(x, rowStart, csr_col, csr_w, dinv,
                                                   aw1, ab1, zlp, n);
    gemm_kernel<128, 32, 8, true, true, true><<<gblk, 256, 0, stream>>>(
        zlp, wt1, b1, hbuf, aw2, ab2, alpha2, n);

    // ---- layer 2 (reordered): y = h@W2t; out = mix_rows(y) + b2 ----
    float* ybuf = zlp;  // reuse
    gemm_kernel<40, 10, 2, false, false, false><<<gblk, 320, 0, stream>>>(
        hbuf, wt2, nullptr, ybuf, nullptr, nullptr, nullptr, n);
    gather40_kernel<<<(n + 3) / 4, 256, 0, stream>>>(ybuf, rowStart, csr_col, csr_w, dinv,
                                                     alpha2, b2, out, n);
}